// Round 3
// baseline (464.138 us; speedup 1.0000x reference)
//
#include <hip/hip_runtime.h>
#include <stdint.h>

// ---------------------------------------------------------------------------
// Fastformer fused pipeline, MI355X gfx950.  Round 3: fp32 inputs/output
// (per reference dtypes); bf16 only for internal MFMA operands.
// Pipeline:
//   1. trans:   WqT/WkT = bf16(transpose(Wq/Wk))
//   2. qaeff:   WqaEffT[h][k] = bf16((Wq@Wqa)^T)
//   3. gemm_qk: Q|K = x @ [Wq|Wk]   (MFMA 128x128 tile, cvt x->bf16 in staging)
//   4. scores:  scores_q = x @ WqaEffT^T  (MFMA, N=16)
//   5. wsum:    sum_e, sum_eq  (e = exp(s/8)*mask)  -> q_ctx
//   6. kaeff:   WkaEffT[b][h][k] = bf16(q_ctx*Wka)  (per-batch)
//   7. scores:  scores_k = K @ WkaEffT^T
//   8. wsum:    sum_e2, sum_e2k -> k_ctx
//   9. mt:      MT[b,h][d'][d] = bf16(k_ctx[d]*Wo[d][d'])
//  10. out:     out = Q + Q_head @ MT^T   (fp32 store, fused +query epilogue)
// ---------------------------------------------------------------------------

typedef __attribute__((ext_vector_type(8))) __bf16    bf16x8;
typedef __attribute__((ext_vector_type(8))) uint16_t  u16x8;
typedef __attribute__((ext_vector_type(4))) float     f32x4;

__device__ __forceinline__ float bf2f(uint16_t v) {
  union { uint32_t u; float f; } x; x.u = ((uint32_t)v) << 16; return x.f;
}
__device__ __forceinline__ uint16_t f2bf(float f) {
  uint32_t u = __float_as_uint(f);
  uint32_t r = (u + 0x7fffu + ((u >> 16) & 1u)) >> 16;
  return (uint16_t)r;
}
__device__ __forceinline__ bf16x8 cvt8(const float4 lo, const float4 hi) {
  u16x8 r;
  r[0] = f2bf(lo.x); r[1] = f2bf(lo.y); r[2] = f2bf(lo.z); r[3] = f2bf(lo.w);
  r[4] = f2bf(hi.x); r[5] = f2bf(hi.y); r[6] = f2bf(hi.z); r[7] = f2bf(hi.w);
  union { u16x8 u; bf16x8 b; } c; c.u = r; return c.b;
}

// ---------------------------------------------------------------------------
// 1. transpose+cvt Wq,Wk (768x768 fp32) -> WT (2 x 768x768 bf16, n-major)
__global__ __launch_bounds__(256) void trans_kernel(
    const float* __restrict__ Wq, const float* __restrict__ Wk,
    uint16_t* __restrict__ WT) {
  int i = blockIdx.x * 256 + threadIdx.x;
  if (i >= 2 * 589824) return;
  int j = (i < 589824) ? i : i - 589824;
  const float* src = (i < 589824) ? Wq : Wk;
  int n = j / 768, k = j - n * 768;
  WT[i] = f2bf(src[k * 768 + n]);  // coalesced write, L2-resident strided read
}

// ---------------------------------------------------------------------------
// 2. WqaEffT[hp][k] = bf16(sum_n Wq[k][n]*Wqa[n][hp]), hp in [0,16)
__global__ __launch_bounds__(256) void qaeff_kernel(
    const float* __restrict__ Wq, const float* __restrict__ Wqa,
    uint16_t* __restrict__ outT) {
  int i = blockIdx.x * 256 + threadIdx.x;  // 768*16
  if (i >= 768 * 16) return;
  int hp = i & 15, k = i >> 4;
  float acc = 0.f;
  if (hp < 12) {
    for (int n = 0; n < 768; n++)
      acc += Wq[k * 768 + n] * Wqa[n * 12 + hp];
  }
  outT[hp * 768 + k] = f2bf(acc);
}

// ---------------------------------------------------------------------------
// 3. big GEMM: C[32768 x 1536] = x @ [Wq | Wk], bf16 out split to Qb/Kb.
//    128x128 block, 4 waves each 64x64, 16x16x32 bf16 MFMA, BK=32.
__global__ __launch_bounds__(256) void gemm_qk(
    const float* __restrict__ X, const uint16_t* __restrict__ WT,
    uint16_t* __restrict__ Qb, uint16_t* __restrict__ Kb) {
  __shared__ __align__(16) uint16_t As[128 * 32];
  __shared__ __align__(16) uint16_t Bs[128 * 32];
  const int tid  = threadIdx.x;
  const int nblk = blockIdx.x;            // 0..11 (6 Q blocks, 6 K blocks)
  const int m0   = blockIdx.y * 128;
  const uint16_t* BT = WT + (size_t)nblk * 98304;  // 128*768; WkT from blk 6
  uint16_t* C   = (nblk < 6) ? Qb : Kb;
  const int cn0 = ((nblk < 6) ? nblk : nblk - 6) * 128;

  const int wave = tid >> 6, lane = tid & 63, lr = lane & 15, lk = lane >> 4;
  const int wm = (wave & 1) * 64, wn = (wave >> 1) * 64;

  const f32x4 zero = {0.f, 0.f, 0.f, 0.f};
  f32x4 acc[4][4];
#pragma unroll
  for (int mi = 0; mi < 4; mi++)
#pragma unroll
    for (int ni = 0; ni < 4; ni++) acc[mi][ni] = zero;

  const int lrow = tid >> 2, lseg = (tid & 3) * 8;

  for (int k0 = 0; k0 < 768; k0 += 32) {
    const float* pa0 = X + (size_t)(m0 + lrow) * 768 + k0 + lseg;
    const float* pa1 = pa0 + (size_t)64 * 768;
    bf16x8 va0 = cvt8(*(const float4*)pa0, *(const float4*)(pa0 + 4));
    bf16x8 va1 = cvt8(*(const float4*)pa1, *(const float4*)(pa1 + 4));
    bf16x8 vb0 = *(const bf16x8*)(BT + (size_t)lrow        * 768 + k0 + lseg);
    bf16x8 vb1 = *(const bf16x8*)(BT + (size_t)(64 + lrow) * 768 + k0 + lseg);
    if (k0) __syncthreads();  // previous iteration's LDS reads done
    *(bf16x8*)(As + tid * 8)        = va0;
    *(bf16x8*)(As + 2048 + tid * 8) = va1;
    *(bf16x8*)(Bs + tid * 8)        = vb0;
    *(bf16x8*)(Bs + 2048 + tid * 8) = vb1;
    __syncthreads();  // LDS writes visible to all waves
    bf16x8 af[4], bfv[4];
#pragma unroll
    for (int mi = 0; mi < 4; mi++)
      af[mi] = *(const bf16x8*)(As + (wm + mi * 16 + lr) * 32 + lk * 8);
#pragma unroll
    for (int ni = 0; ni < 4; ni++)
      bfv[ni] = *(const bf16x8*)(Bs + (wn + ni * 16 + lr) * 32 + lk * 8);
#pragma unroll
    for (int mi = 0; mi < 4; mi++)
#pragma unroll
      for (int ni = 0; ni < 4; ni++)
        acc[mi][ni] = __builtin_amdgcn_mfma_f32_16x16x32_bf16(
            af[mi], bfv[ni], acc[mi][ni], 0, 0, 0);
  }
  // C/D layout: col = lane&15, row = (lane>>4)*4 + reg   [m89/m91 verified]
#pragma unroll
  for (int mi = 0; mi < 4; mi++)
#pragma unroll
    for (int ni = 0; ni < 4; ni++) {
      const int col = cn0 + wn + ni * 16 + lr;
#pragma unroll
      for (int r = 0; r < 4; r++) {
        const int row = m0 + wm + mi * 16 + lk * 4 + r;
        C[(size_t)row * 768 + col] = f2bf(acc[mi][ni][r]);
      }
    }
}

// ---------------------------------------------------------------------------
// 4/7. scores[32768 x 16] = A @ BT^T   (BT: [16][768] bf16, per-batch option)
template <bool AF32>
__global__ __launch_bounds__(256) void scores_kernel(
    const void* __restrict__ Av, const uint16_t* __restrict__ BT,
    int bStride, float* __restrict__ scores) {
  __shared__ __align__(16) uint16_t Bs[16 * 768];  // 24 KB, loaded once
  __shared__ __align__(16) uint16_t As[64 * 32];
  const int tid = threadIdx.x;
  const int m0  = blockIdx.x * 64;
  const uint16_t* BTb = BT + (size_t)(m0 >> 12) * bStride;  // batch = m0/4096
#pragma unroll
  for (int p = 0; p < 6; p++)
    *(bf16x8*)(Bs + (p * 256 + tid) * 8) =
        *(const bf16x8*)(BTb + (size_t)(p * 256 + tid) * 8);
  const int wave = tid >> 6, lane = tid & 63, lr = lane & 15, lk = lane >> 4;
  const f32x4 zero = {0.f, 0.f, 0.f, 0.f};
  f32x4 acc = zero;
  const int lrow = tid >> 2, lseg = (tid & 3) * 8;
  for (int k0 = 0; k0 < 768; k0 += 32) {
    bf16x8 va;
    if constexpr (AF32) {
      const float* p = (const float*)Av + (size_t)(m0 + lrow) * 768 + k0 + lseg;
      va = cvt8(*(const float4*)p, *(const float4*)(p + 4));
    } else {
      va = *(const bf16x8*)((const uint16_t*)Av +
                            (size_t)(m0 + lrow) * 768 + k0 + lseg);
    }
    if (k0) __syncthreads();
    *(bf16x8*)(As + tid * 8) = va;
    __syncthreads();
    bf16x8 af  = *(const bf16x8*)(As + (wave * 16 + lr) * 32 + lk * 8);
    bf16x8 bfv = *(const bf16x8*)(Bs + lr * 768 + k0 + lk * 8);
    acc = __builtin_amdgcn_mfma_f32_16x16x32_bf16(af, bfv, acc, 0, 0, 0);
  }
#pragma unroll
  for (int r = 0; r < 4; r++) {
    const int row = m0 + wave * 16 + lk * 4 + r;
    scores[row * 16 + lr] = acc[r];
  }
}

// ---------------------------------------------------------------------------
// 5/8. weighted sums: sumv[b][col] += sum_s e*V, sume[b][h] += sum_s e
__global__ __launch_bounds__(256) void wsum_kernel(
    const uint16_t* __restrict__ V, const float* __restrict__ scores,
    const float* __restrict__ mask, float* __restrict__ sumv,
    float* __restrict__ sume) {
  const int tid = threadIdx.x;
  const int cg = blockIdx.x, sc = blockIdx.y, b = blockIdx.z;
  const int col = cg * 256 + tid;
  const int h = col >> 6;
  float accv = 0.f, acce = 0.f;
  const int s0 = sc * 128;
  for (int i = 0; i < 128; i++) {
    const size_t row = (size_t)b * 4096 + s0 + i;
    const float e = __expf(scores[row * 16 + h] * 0.125f) * mask[row];
    accv += e * bf2f(V[row * 768 + col]);
    acce += e;
  }
  atomicAdd(&sumv[b * 768 + col], accv);
  if ((col & 63) == 0) atomicAdd(&sume[b * 12 + h], acce);
}

// ---------------------------------------------------------------------------
// q_ctx = sum_eq / (sum_e + 1e-8)
__global__ __launch_bounds__(256) void qctx_kernel(
    const float* __restrict__ sumv, const float* __restrict__ sume,
    float* __restrict__ qctx) {
  int i = blockIdx.x * 256 + threadIdx.x;
  if (i >= 8 * 768) return;
  int b = i / 768, hd = i - b * 768, h = hd >> 6;
  qctx[i] = sumv[i] / (sume[b * 12 + h] + 1e-8f);
}

// ---------------------------------------------------------------------------
// 6. WkaEffT[b][hp][k] = bf16(q_ctx[b][k] * Wka[k][hp])
__global__ __launch_bounds__(256) void kaeff_kernel(
    const float* __restrict__ qctx, const float* __restrict__ Wka,
    uint16_t* __restrict__ outT) {
  int i = blockIdx.x * 256 + threadIdx.x;
  if (i >= 8 * 16 * 768) return;
  int k = i % 768, hp = (i / 768) & 15, b = i / 12288;
  float v = 0.f;
  if (hp < 12) v = qctx[b * 768 + k] * Wka[k * 12 + hp];
  outT[i] = f2bf(v);
}

// ---------------------------------------------------------------------------
// 9. MT[bh][dp][d] = k_ctx[b,h,d]*Wo[d][dp]; k_ctx = q_ctx*sum_e2k/(sum_e2+eps)
__global__ __launch_bounds__(256) void mt_kernel(
    const float* __restrict__ qctx, const float* __restrict__ sumv2,
    const float* __restrict__ sume2, const float* __restrict__ Wo,
    uint16_t* __restrict__ MT) {
  int i = blockIdx.x * 256 + threadIdx.x;  // 96*4096
  int d = i & 63, dp = (i >> 6) & 63, bh = i >> 12;
  int b = bh / 12, h = bh - b * 12;
  int hd = h * 64 + d;
  float kc = qctx[b * 768 + hd] * sumv2[b * 768 + hd] / (sume2[b * 12 + h] + 1e-8f);
  MT[i] = f2bf(kc * Wo[d * 64 + dp]);
}

// ---------------------------------------------------------------------------
// 10. out[row][h*64+n] = Q[row][h*64+n] + sum_d Qh[row][d]*MT[bh][n][d]
__global__ __launch_bounds__(256) void out_kernel(
    const uint16_t* __restrict__ Qb, const uint16_t* __restrict__ MT,
    float* __restrict__ out) {
  __shared__ __align__(16) uint16_t Qs[128 * 64];
  __shared__ __align__(16) uint16_t Ms[64 * 64];
  const int tid = threadIdx.x;
  const int bh = blockIdx.x, rb = blockIdx.y;
  const int b = bh / 12, h = bh - b * 12;
  const size_t rowbase = (size_t)b * 4096 + rb * 128;
  const uint16_t* Aptr = Qb + rowbase * 768 + h * 64;
  *(bf16x8*)(Ms + tid * 8)        = *(const bf16x8*)(MT + (size_t)bh * 4096 + tid * 8);
  *(bf16x8*)(Ms + 2048 + tid * 8) = *(const bf16x8*)(MT + (size_t)bh * 4096 + 2048 + tid * 8);
#pragma unroll
  for (int p = 0; p < 4; p++) {
    const int c = p * 256 + tid;
    *(bf16x8*)(Qs + c * 8) =
        *(const bf16x8*)(Aptr + (size_t)(c >> 3) * 768 + (c & 7) * 8);
  }
  __syncthreads();
  const int wave = tid >> 6, lane = tid & 63, lr = lane & 15, lk = lane >> 4;
  const f32x4 zero = {0.f, 0.f, 0.f, 0.f};
  f32x4 acc[2][4];
#pragma unroll
  for (int mi = 0; mi < 2; mi++)
#pragma unroll
    for (int ni = 0; ni < 4; ni++) acc[mi][ni] = zero;
#pragma unroll
  for (int kc = 0; kc < 2; kc++) {
    bf16x8 af[2], bfv[4];
#pragma unroll
    for (int mi = 0; mi < 2; mi++)
      af[mi] = *(const bf16x8*)(Qs + (wave * 32 + mi * 16 + lr) * 64 + kc * 32 + lk * 8);
#pragma unroll
    for (int ni = 0; ni < 4; ni++)
      bfv[ni] = *(const bf16x8*)(Ms + (ni * 16 + lr) * 64 + kc * 32 + lk * 8);
#pragma unroll
    for (int mi = 0; mi < 2; mi++)
#pragma unroll
      for (int ni = 0; ni < 4; ni++)
        acc[mi][ni] = __builtin_amdgcn_mfma_f32_16x16x32_bf16(
            af[mi], bfv[ni], acc[mi][ni], 0, 0, 0);
  }
#pragma unroll
  for (int mi = 0; mi < 2; mi++)
#pragma unroll
    for (int ni = 0; ni < 4; ni++)
#pragma unroll
      for (int r = 0; r < 4; r++) {
        const int row = wave * 32 + mi * 16 + lk * 4 + r;
        const int col = ni * 16 + lr;
        const float q = bf2f(Qs[row * 64 + col]);
        out[(rowbase + row) * 768 + h * 64 + col] = q + acc[mi][ni][r];
      }
}

// ---------------------------------------------------------------------------
extern "C" void kernel_launch(void* const* d_in, const int* in_sizes, int n_in,
                              void* d_out, int out_size, void* d_ws, size_t ws_size,
                              hipStream_t stream) {
  const float* x    = (const float*)d_in[0];
  const float* mask = (const float*)d_in[1];
  const float* Wq   = (const float*)d_in[2];
  const float* Wk   = (const float*)d_in[3];
  const float* Wqa  = (const float*)d_in[4];
  const float* Wka  = (const float*)d_in[5];
  const float* Wo   = (const float*)d_in[6];
  float* out = (float*)d_out;
  char* ws = (char*)d_ws;

  // workspace layout (bytes)
  uint16_t* Qb    = (uint16_t*)(ws);                    // 50331648
  uint16_t* Kb    = (uint16_t*)(ws + 50331648);         // 50331648
  uint16_t* WT    = (uint16_t*)(ws + 100663296);        // 2359296
  uint16_t* WqaT  = (uint16_t*)(ws + 103022592);        // 24576
  uint16_t* WkaT  = (uint16_t*)(ws + 103047168);        // 196608
  float*    scq   = (float*)   (ws + 103243776);        // 2097152
  float*    sck   = (float*)   (ws + 105340928);        // 2097152
  uint16_t* MT    = (uint16_t*)(ws + 107438080);        // 786432
  float*    accum = (float*)   (ws + 108224512);        // 49920
  float* sume   = accum;               // 96
  float* sume2  = accum + 96;          // 96
  float* sumeq  = accum + 192;         // 6144
  float* sume2k = accum + 192 + 6144;  // 6144
  float* qctx   = (float*)(ws + 108274432);             // 24576

  // zero the atomic accumulators (ws is poisoned 0xAA each call)
  hipMemsetAsync(accum, 0, 12480 * sizeof(float), stream);

  trans_kernel<<<4608, 256, 0, stream>>>(Wq, Wk, WT);
  qaeff_kernel<<<48, 256, 0, stream>>>(Wq, Wqa, WqaT);
  gemm_qk<<<dim3(12, 256), 256, 0, stream>>>(x, WT, Qb, Kb);
  scores_kernel<true><<<512, 256, 0, stream>>>(x, WqaT, 0, scq);
  wsum_kernel<<<dim3(3, 32, 8), 256, 0, stream>>>(Qb, scq, mask, sumeq, sume);
  qctx_kernel<<<24, 256, 0, stream>>>(sumeq, sume, qctx);
  kaeff_kernel<<<384, 256, 0, stream>>>(qctx, Wka, WkaT);
  scores_kernel<false><<<512, 256, 0, stream>>>(Kb, WkaT, 16 * 768, sck);
  wsum_kernel<<<dim3(3, 32, 8), 256, 0, stream>>>(Kb, sck, mask, sume2k, sume2);
  mt_kernel<<<1536, 256, 0, stream>>>(qctx, sume2k, sume2, Wo, MT);
  out_kernel<<<dim3(96, 32), 256, 0, stream>>>(Qb, MT, out);
}

// Round 4
// 365.572 us; speedup vs baseline: 1.2696x; 1.2696x over previous
//
#include <hip/hip_runtime.h>
#include <stdint.h>

// ---------------------------------------------------------------------------
// Fastformer fused pipeline, MI355X gfx950.  Round 4:
//  - global_load_lds (16B) staging everywhere (round-1 NaN was dtype, not DMA)
//  - x pre-converted to bf16 (Xb) stored in d_out's first 50 MB (dead until
//    the final kernel); gemm stages pure bf16 -> half the staging bytes
//  - XCD swizzle: 12 same-m0 column blocks -> same XCD, consecutive slots
//  - fusions: scores_q from Qb (kills qaeff matmul), scores+wsum one kernel
//    (e in LDS), qctx+kaeff one kernel, MT computed inside out_kernel.
// Launches: memset, prep, gemm_qk, scoresum(q), ctxkaeff, scoresum(k), out.
// ---------------------------------------------------------------------------

#define AS1 __attribute__((address_space(1)))
#define AS3 __attribute__((address_space(3)))

typedef __attribute__((ext_vector_type(8))) __bf16   bf16x8;
typedef __attribute__((ext_vector_type(8))) uint16_t u16x8;
typedef __attribute__((ext_vector_type(4))) float    f32x4;

__device__ __forceinline__ float bf2f(uint16_t v) {
  union { uint32_t u; float f; } x; x.u = ((uint32_t)v) << 16; return x.f;
}
__device__ __forceinline__ uint16_t f2bf(float f) {
  uint32_t u = __float_as_uint(f);
  uint32_t r = (u + 0x7fffu + ((u >> 16) & 1u)) >> 16;
  return (uint16_t)r;
}
__device__ __forceinline__ bf16x8 cvt8(const float4 lo, const float4 hi) {
  u16x8 r;
  r[0] = f2bf(lo.x); r[1] = f2bf(lo.y); r[2] = f2bf(lo.z); r[3] = f2bf(lo.w);
  r[4] = f2bf(hi.x); r[5] = f2bf(hi.y); r[6] = f2bf(hi.z); r[7] = f2bf(hi.w);
  union { u16x8 u; bf16x8 b; } c; c.u = r; return c.b;
}
// async global->LDS, 16 B/lane; LDS dest must be lane-contiguous (tid*16B).
__device__ __forceinline__ void gload16(const void* g, void* l) {
  __builtin_amdgcn_global_load_lds((AS1 void*)(void*)g, (AS3 void*)l, 16, 0, 0);
}

// ---------------------------------------------------------------------------
// prep: job0 cvt X->Xb (12288 blocks) | job1 WT=bf16(Wq^T|Wk^T) (4608)
//       | job2 WqaT[hp][k]=bf16(Wqa[k][hp]) (48)
__global__ __launch_bounds__(256) void prep_kernel(
    const float* __restrict__ X, const float* __restrict__ Wq,
    const float* __restrict__ Wk, const float* __restrict__ Wqa,
    uint16_t* __restrict__ Xb, uint16_t* __restrict__ WT,
    uint16_t* __restrict__ WqaT) {
  const int bid = blockIdx.x, tid = threadIdx.x;
  if (bid < 12288) {
    size_t i = ((size_t)bid * 256 + tid) * 8;
    const float* p = X + i;
    *(bf16x8*)(Xb + i) = cvt8(*(const float4*)p, *(const float4*)(p + 4));
  } else if (bid < 16896) {
    int i = (bid - 12288) * 256 + tid;          // 0..1179647
    int j = (i < 589824) ? i : i - 589824;
    const float* src = (i < 589824) ? Wq : Wk;
    int n = j / 768, k = j - n * 768;
    WT[i] = f2bf(src[k * 768 + n]);
  } else {
    int i = (bid - 16896) * 256 + tid;          // 0..12287
    int hp = i / 768, k = i - hp * 768;
    WqaT[i] = (hp < 12) ? f2bf(Wqa[k * 12 + hp]) : (uint16_t)0;
  }
}

// ---------------------------------------------------------------------------
// gemm: C[32768 x 1536] = Xb @ WT^T, bf16 out split Qb/Kb. 128x128 block,
// 4 waves x (64x64), 16x16x32 MFMA, BK=32, full DMA staging, XCD swizzle.
__global__ __launch_bounds__(256) void gemm_qk(
    const uint16_t* __restrict__ Xb, const uint16_t* __restrict__ WT,
    uint16_t* __restrict__ Qb, uint16_t* __restrict__ Kb) {
  __shared__ __align__(16) uint16_t As[128 * 32];
  __shared__ __align__(16) uint16_t Bs[128 * 32];
  const int tid = threadIdx.x;
  // swizzle: same-m0 column blocks -> same XCD (bid%8), consecutive slots
  const int bid = blockIdx.x;              // 0..3071
  const int xr = bid & 7, th = bid >> 3;   // th: 0..383
  const int nblk = th % 12;
  const int m0 = ((th / 12) * 8 + xr) * 128;
  const uint16_t* BT = WT + (size_t)nblk * 98304;
  uint16_t* C   = (nblk < 6) ? Qb : Kb;
  const int cn0 = ((nblk < 6) ? nblk : nblk - 6) * 128;

  const int wave = tid >> 6, lane = tid & 63, lr = lane & 15, lk = lane >> 4;
  const int wm = (wave & 1) * 64, wn = (wave >> 1) * 64;

  const f32x4 zero = {0.f, 0.f, 0.f, 0.f};
  f32x4 acc[4][4];
#pragma unroll
  for (int mi = 0; mi < 4; mi++)
#pragma unroll
    for (int ni = 0; ni < 4; ni++) acc[mi][ni] = zero;

  const int lrow = tid >> 2, lseg = (tid & 3) * 8;

  for (int k0 = 0; k0 < 768; k0 += 32) {
    gload16(Xb + (size_t)(m0 + lrow)      * 768 + k0 + lseg, As + tid * 8);
    gload16(Xb + (size_t)(m0 + 64 + lrow) * 768 + k0 + lseg, As + 2048 + tid * 8);
    gload16(BT + (size_t)lrow        * 768 + k0 + lseg, Bs + tid * 8);
    gload16(BT + (size_t)(64 + lrow) * 768 + k0 + lseg, Bs + 2048 + tid * 8);
    __syncthreads();  // drains vmcnt (DMA) before LDS reads
    bf16x8 af[4], bfv[4];
#pragma unroll
    for (int mi = 0; mi < 4; mi++)
      af[mi] = *(const bf16x8*)(As + (wm + mi * 16 + lr) * 32 + lk * 8);
#pragma unroll
    for (int ni = 0; ni < 4; ni++)
      bfv[ni] = *(const bf16x8*)(Bs + (wn + ni * 16 + lr) * 32 + lk * 8);
#pragma unroll
    for (int mi = 0; mi < 4; mi++)
#pragma unroll
      for (int ni = 0; ni < 4; ni++)
        acc[mi][ni] = __builtin_amdgcn_mfma_f32_16x16x32_bf16(
            af[mi], bfv[ni], acc[mi][ni], 0, 0, 0);
    __syncthreads();  // protect LDS from next iteration's DMA
  }
  // C/D layout: col = lane&15, row = (lane>>4)*4 + reg
#pragma unroll
  for (int mi = 0; mi < 4; mi++)
#pragma unroll
    for (int ni = 0; ni < 4; ni++) {
      const int col = cn0 + wn + ni * 16 + lr;
#pragma unroll
      for (int r = 0; r < 4; r++) {
        const int row = m0 + wm + mi * 16 + lk * 4 + r;
        C[(size_t)row * 768 + col] = f2bf(acc[mi][ni][r]);
      }
    }
}

// ---------------------------------------------------------------------------
// scoresum: per 64-row block. Phase 1: scores = A @ BT^T (MFMA, N=16),
// e = exp(s/8)*mask into LDS. Phase 2: sumv[b][col] += e*A, sume[b][h] += e.
__global__ __launch_bounds__(256) void scoresum_kernel(
    const uint16_t* __restrict__ A,      // 32768x768 bf16 (Qb or Kb); also V
    const uint16_t* __restrict__ BT,     // [16][768] bf16 (+bStride per batch)
    const float* __restrict__ mask,
    int bStride,
    float* __restrict__ sumv, float* __restrict__ sume) {
  __shared__ __align__(16) uint16_t Bs[16 * 768];  // 24 KB
  __shared__ __align__(16) uint16_t As[64 * 32];   // 4 KB
  __shared__ float eS[64 * 16];                    // 4 KB
  const int tid = threadIdx.x;
  const int m0  = blockIdx.x * 64;
  const int b   = m0 >> 12;
  const uint16_t* BTb = BT + (size_t)b * bStride;
#pragma unroll
  for (int p = 0; p < 6; p++)
    gload16(BTb + (size_t)(p * 256 + tid) * 8, Bs + (p * 256 + tid) * 8);
  const int wave = tid >> 6, lane = tid & 63, lr = lane & 15, lk = lane >> 4;
  const f32x4 zero = {0.f, 0.f, 0.f, 0.f};
  f32x4 acc = zero;
  const int lrow = tid >> 2, lseg = (tid & 3) * 8;
  for (int k0 = 0; k0 < 768; k0 += 32) {
    gload16(A + (size_t)(m0 + lrow) * 768 + k0 + lseg, As + tid * 8);
    __syncthreads();
    bf16x8 af  = *(const bf16x8*)(As + (wave * 16 + lr) * 32 + lk * 8);
    bf16x8 bfv = *(const bf16x8*)(Bs + lr * 768 + k0 + lk * 8);
    acc = __builtin_amdgcn_mfma_f32_16x16x32_bf16(af, bfv, acc, 0, 0, 0);
    __syncthreads();
  }
  // e into LDS: row = wave*16 + lk*4 + r, col(h) = lr
#pragma unroll
  for (int r = 0; r < 4; r++) {
    const int row = wave * 16 + lk * 4 + r;
    eS[row * 16 + lr] = __expf(acc[r] * 0.125f) * mask[m0 + row];
  }
  __syncthreads();
  if (tid < 12) {  // per-h partial sum of e
    float s = 0.f;
    for (int r = 0; r < 64; r++) s += eS[r * 16 + tid];
    atomicAdd(&sume[b * 12 + tid], s);
  }
  // weighted sums: cols {tid, 256+tid, 512+tid}; h = p*4 + wave (uniform)
  float a0 = 0.f, a1 = 0.f, a2 = 0.f;
  const uint16_t* V = A + (size_t)m0 * 768;
  for (int row = 0; row < 64; row++) {
    const uint16_t* Vr = V + (size_t)row * 768;
    const float* er = eS + row * 16;
    a0 += er[wave]     * bf2f(Vr[tid]);
    a1 += er[4 + wave] * bf2f(Vr[256 + tid]);
    a2 += er[8 + wave] * bf2f(Vr[512 + tid]);
  }
  atomicAdd(&sumv[b * 768 + tid],       a0);
  atomicAdd(&sumv[b * 768 + 256 + tid], a1);
  atomicAdd(&sumv[b * 768 + 512 + tid], a2);
}

// ---------------------------------------------------------------------------
// ctxkaeff: qctx = sumeq/(sume+eps); WkaT[b][hp][k] = bf16(qctx*Wka[k][hp])
__global__ __launch_bounds__(256) void ctxkaeff_kernel(
    const float* __restrict__ sumeq, const float* __restrict__ sume,
    const float* __restrict__ Wka, uint16_t* __restrict__ WkaT,
    float* __restrict__ qctx) {
  int i = blockIdx.x * 256 + threadIdx.x;  // 8*16*768
  int k = i % 768, hp = (i / 768) & 15, b = i / 12288;
  float qc = sumeq[b * 768 + k] / (sume[b * 12 + (k >> 6)] + 1e-8f);
  WkaT[i] = (hp < 12) ? f2bf(qc * Wka[k * 12 + hp]) : (uint16_t)0;
  if (hp == 0) qctx[b * 768 + k] = qc;
}

// ---------------------------------------------------------------------------
// out: per (bh, 128-row block): Ms[n][d] = bf16(kc[d]*Wo[d][n]) computed
// in-block; out = Q + Qh @ Ms^T (fp32 store).
__global__ __launch_bounds__(256) void out_kernel(
    const uint16_t* __restrict__ Qb,
    const float* __restrict__ qctx, const float* __restrict__ sumv2,
    const float* __restrict__ sume2, const float* __restrict__ Wo,
    float* __restrict__ out) {
  __shared__ __align__(16) uint16_t Qs[128 * 64];  // 16 KB
  __shared__ __align__(16) uint16_t Ms[64 * 64];   // 8 KB
  __shared__ float kcS[64];
  const int tid = threadIdx.x;
  const int bh = blockIdx.x, rb = blockIdx.y;
  const int b = bh / 12, h = bh - b * 12;
  const size_t rowbase = (size_t)b * 4096 + rb * 128;
  const uint16_t* Aptr = Qb + rowbase * 768 + h * 64;
#pragma unroll
  for (int p = 0; p < 4; p++) {
    const int c = p * 256 + tid;
    gload16(Aptr + (size_t)(c >> 3) * 768 + (c & 7) * 8, Qs + c * 8);
  }
  if (tid < 64) {
    const int hd = h * 64 + tid;
    kcS[tid] = qctx[b * 768 + hd] * sumv2[b * 768 + hd] /
               (sume2[b * 12 + h] + 1e-8f);
  }
  __syncthreads();  // kcS ready (also drains Qs DMA)
#pragma unroll
  for (int p = 0; p < 16; p++) {
    const int i = p * 256 + tid;
    const int d = i & 63, n = i >> 6;
    Ms[i] = f2bf(kcS[d] * Wo[d * 64 + n]);
  }
  __syncthreads();  // Ms + Qs visible
  const int wave = tid >> 6, lane = tid & 63, lr = lane & 15, lk = lane >> 4;
  const f32x4 zero = {0.f, 0.f, 0.f, 0.f};
  f32x4 acc[2][4];
#pragma unroll
  for (int mi = 0; mi < 2; mi++)
#pragma unroll
    for (int ni = 0; ni < 4; ni++) acc[mi][ni] = zero;
#pragma unroll
  for (int kc = 0; kc < 2; kc++) {
    bf16x8 af[2], bfv[4];
#pragma unroll
    for (int mi = 0; mi < 2; mi++)
      af[mi] = *(const bf16x8*)(Qs + (wave * 32 + mi * 16 + lr) * 64 + kc * 32 + lk * 8);
#pragma unroll
    for (int ni = 0; ni < 4; ni++)
      bfv[ni] = *(const bf16x8*)(Ms + (ni * 16 + lr) * 64 + kc * 32 + lk * 8);
#pragma unroll
    for (int mi = 0; mi < 2; mi++)
#pragma unroll
      for (int ni = 0; ni < 4; ni++)
        acc[mi][ni] = __builtin_amdgcn_mfma_f32_16x16x32_bf16(
            af[mi], bfv[ni], acc[mi][ni], 0, 0, 0);
  }
#pragma unroll
  for (int mi = 0; mi < 2; mi++)
#pragma unroll
    for (int ni = 0; ni < 4; ni++)
#pragma unroll
      for (int r = 0; r < 4; r++) {
        const int row = wave * 32 + mi * 16 + lk * 4 + r;
        const int col = ni * 16 + lr;
        const float q = bf2f(Qs[row * 64 + col]);
        out[(rowbase + row) * 768 + h * 64 + col] = q + acc[mi][ni][r];
      }
}

// ---------------------------------------------------------------------------
extern "C" void kernel_launch(void* const* d_in, const int* in_sizes, int n_in,
                              void* d_out, int out_size, void* d_ws, size_t ws_size,
                              hipStream_t stream) {
  const float* x    = (const float*)d_in[0];
  const float* mask = (const float*)d_in[1];
  const float* Wq   = (const float*)d_in[2];
  const float* Wk   = (const float*)d_in[3];
  const float* Wqa  = (const float*)d_in[4];
  const float* Wka  = (const float*)d_in[5];
  const float* Wo   = (const float*)d_in[6];
  float* out = (float*)d_out;
  char* ws = (char*)d_ws;

  // Xb (bf16 x) lives in d_out's first 50 MB — dead by the time out_kernel
  // writes. out_size = 25165824 fp32 = 100.7 MB >= 50.4 MB needed.
  uint16_t* Xb = (uint16_t*)d_out;

  // workspace layout (bytes); total ~103.3 MB (proven budget from round 3)
  uint16_t* Qb    = (uint16_t*)(ws);                    // 50331648
  uint16_t* Kb    = (uint16_t*)(ws + 50331648);         // 50331648
  uint16_t* WT    = (uint16_t*)(ws + 100663296);        // 2359296
  uint16_t* WqaT  = (uint16_t*)(ws + 103022592);        // 24576
  uint16_t* WkaT  = (uint16_t*)(ws + 103047168);        // 196608
  float*    accum = (float*)   (ws + 103243776);        // 49920
  float* sume   = accum;               // 96
  float* sume2  = accum + 96;          // 96
  float* sumeq  = accum + 192;         // 6144
  float* sume2k = accum + 192 + 6144;  // 6144
  float* qctx   = (float*)(ws + 103293696);             // 24576

  hipMemsetAsync(accum, 0, 12480 * sizeof(float), stream);

  prep_kernel<<<16944, 256, 0, stream>>>(x, Wq, Wk, Wqa, Xb, WT, WqaT);
  gemm_qk<<<3072, 256, 0, stream>>>(Xb, WT, Qb, Kb);
  scoresum_kernel<<<512, 256, 0, stream>>>(Qb, WqaT, mask, 0, sumeq, sume);
  ctxkaeff_kernel<<<384, 256, 0, stream>>>(sumeq, sume, Wka, WkaT, qctx);
  scoresum_kernel<<<512, 256, 0, stream>>>(Kb, WkaT, mask, 12288, sume2k, sume2);
  out_kernel<<<dim3(96, 32), 256, 0, stream>>>(Qb, qctx, sume2k, sume2, Wo, out);
}